// Round 11
// baseline (487.500 us; speedup 1.0000x reference)
//
#include <hip/hip_runtime.h>

typedef float f4 __attribute__((ext_vector_type(4)));
typedef float f2 __attribute__((ext_vector_type(2)));
typedef short s8v __attribute__((ext_vector_type(8)));        // 8 bf16
typedef unsigned int u2v __attribute__((ext_vector_type(2)));
typedef unsigned int u4v __attribute__((ext_vector_type(4)));

#define B_ 32
#define T_ 1024
#define J_ 128
#define D_ 256

__device__ inline unsigned short f2bf(float x) {
    unsigned int u = __float_as_uint(x);
    u += 0x7fffu + ((u >> 16) & 1u);      // RNE
    return (unsigned short)(u >> 16);
}

__device__ __forceinline__ void ldsload16(const void* g, void* l) {
    __builtin_amdgcn_global_load_lds(
        (const __attribute__((address_space(1))) void*)g,
        (__attribute__((address_space(3))) void*)l, 16, 0, 0);
}

// ---------------- K_pre: fused Bqh = bf16(w3*q+w1), sq = q.w2, qTh = bf16 transpose; zero sync ctrl ----------------
__global__ __launch_bounds__(256) void k_pre(const float* __restrict__ q, const float* __restrict__ w,
                                             unsigned short* __restrict__ Bqh, float* __restrict__ sq,
                                             unsigned short* __restrict__ qTh, unsigned int* __restrict__ ctrl) {
    __shared__ float t_[16][260];
    int b = blockIdx.x >> 3, jt = blockIdx.x & 7;
    int tid = threadIdx.x;
    if (blockIdx.x == 0 && tid < 64) ctrl[tid] = 0u;    // cnt[32] + done[32], re-zeroed every call
    const float* qb = q + (b * J_ + jt * 16) * D_;

#pragma unroll
    for (int k = 0; k < 4; k++) {
        int idx = tid + (k << 8);              // f4 id over 16x64
        int jj = idx >> 6, d4 = idx & 63;
        f4 v = *(const f4*)(qb + jj * D_ + (d4 << 2));
        *(f4*)&t_[jj][d4 << 2] = v;
        f4 w1v = *(const f4*)(w + (d4 << 2));
        f4 w3v = *(const f4*)(w + 2 * D_ + (d4 << 2));
        u2v p;
        p[0] = (unsigned int)f2bf(w3v[0] * v[0] + w1v[0]) | ((unsigned int)f2bf(w3v[1] * v[1] + w1v[1]) << 16);
        p[1] = (unsigned int)f2bf(w3v[2] * v[2] + w1v[2]) | ((unsigned int)f2bf(w3v[3] * v[3] + w1v[3]) << 16);
        *(u2v*)(Bqh + (b * J_ + jt * 16 + jj) * D_ + (d4 << 2)) = p;
    }
    __syncthreads();

    // sq: 16 threads per j row
    {
        int jj = tid >> 4, dg = tid & 15;
        float p = 0.f;
#pragma unroll
        for (int i = 0; i < 16; i++) {
            int d = (dg << 4) + i;
            p += t_[jj][d] * w[D_ + d];
        }
#pragma unroll
        for (int m = 8; m >= 1; m >>= 1) p += __shfl_xor(p, m);
        if (dg == 0) sq[b * J_ + jt * 16 + jj] = p;
    }

    // qT: thread = d; write 16 j's (32 B) as two u4v
    {
        int dd = tid;
        unsigned int pk[8];
#pragma unroll
        for (int i = 0; i < 8; i++) {
            pk[i] = (unsigned int)f2bf(t_[2 * i][dd]) | ((unsigned int)f2bf(t_[2 * i + 1][dd]) << 16);
        }
        u4v v0, v1;
        v0[0] = pk[0]; v0[1] = pk[1]; v0[2] = pk[2]; v0[3] = pk[3];
        v1[0] = pk[4]; v1[1] = pk[5]; v1[2] = pk[6]; v1[3] = pk[7];
        unsigned short* dst = qTh + (b * D_ + dd) * J_ + jt * 16;
        *(u4v*)dst = v0;
        *(u4v*)(dst + 8) = v1;
    }
}

// ---------------- K2: MFMA S -> softmax -> MFMA PV -> q1,q2,q3 + partials -> per-batch sync -> quarter 4 ----------------
__global__ __launch_bounds__(256, 4) void k_main(const float* __restrict__ ctx,
                                                 const unsigned short* __restrict__ Bqh,
                                                 const unsigned short* __restrict__ qTh,
                                                 const float* __restrict__ sq,
                                                 float* __restrict__ pq2c, float* __restrict__ pms,
                                                 float* __restrict__ q2cf, unsigned int* __restrict__ ctrl,
                                                 float* __restrict__ out) {
    __shared__ __align__(16) char lds[40960];
    char* B0 = lds;                     // 16 KB
    char* B1 = lds + 16384;             // 16 KB
    char* Ps = lds + 32768;             // 8 KB: P 32x128 bf16, swizzled
    float* sc = (float*)B1;             // 512 B overlay: live only between S5 and S6

    int bid = blockIdx.x;
    int b  = bid >> 5;                  // contiguous: batch's 32 blocks dispatched adjacently
    int tc = bid & 31;
    int t0 = tc << 5;
    int tid = threadIdx.x;
    int w = tid >> 6, l = tid & 63, lr = l & 15, lq = l >> 4;
    int rg = w & 1, ch = w >> 1;          // row-group / j-half (phase A), d-half (phase B, partial)
    int R0 = rg << 4;

    const unsigned short* BqB  = Bqh + b * J_ * D_;
    const unsigned short* qThB = qTh + b * D_ * J_;

    auto stageBq = [&](char* buf, int qt) {
#pragma unroll
        for (int i = 0; i < 4; i++) {
            int g = tid + (i << 8);
            int jr = g >> 3, c = g & 7;
            ldsload16(BqB + jr * D_ + (qt << 6) + ((c ^ (jr & 7)) << 3),
                      buf + (i << 12) + (w << 10));
        }
    };
    auto stageQ = [&](char* buf, int st) {
#pragma unroll
        for (int i = 0; i < 4; i++) {
            int g = tid + (i << 8);
            int dr = g >> 4, c = g & 15;
            ldsload16(qThB + ((st << 6) + dr) * J_ + ((c ^ (dr & 7)) << 3),
                      buf + (i << 12) + (w << 10));
        }
    };

    f4 acc[4];
#pragma unroll
    for (int nf = 0; nf < 4; nf++) acc[nf] = (f4){0.f, 0.f, 0.f, 0.f};

    stageBq(B0, 0);
    stageBq(B1, 1);

    // ctx rows -> bf16 A-frags
    const float* ctxA = ctx + (b * T_ + t0 + R0 + lr) * D_;
    s8v af[8];
#pragma unroll
    for (int k = 0; k < 8; k++) {
        f4 a0 = *(const f4*)(ctxA + k * 32 + lq * 8);
        f4 a1 = *(const f4*)(ctxA + k * 32 + lq * 8 + 4);
        union { unsigned short u[8]; s8v v; } t;
#pragma unroll
        for (int e = 0; e < 4; e++) { t.u[e] = f2bf(a0[e]); t.u[e + 4] = f2bf(a1[e]); }
        af[k] = t.v;
    }

    auto mfmaA = [&](char* buf, int qt) {
#pragma unroll
        for (int kk = 0; kk < 2; kk++)
#pragma unroll
            for (int nf = 0; nf < 4; nf++) {
                int jr = (ch << 6) + (nf << 4) + lr;
                s8v bv = *(const s8v*)(buf + (jr << 7) + ((((kk << 2) | lq) ^ (jr & 7)) << 4));
                acc[nf] = __builtin_amdgcn_mfma_f32_16x16x32_bf16(af[(qt << 1) | kk], bv, acc[nf], 0, 0, 0);
            }
    };

    __syncthreads();               // S1: q0,q1 staged
    mfmaA(B0, 0);
    __syncthreads();               // S2: B0 free
    stageBq(B0, 2);
    mfmaA(B1, 1);
    __syncthreads();               // S3: q2 staged, B1 free
    stageBq(B1, 3);
    mfmaA(B0, 2);
    __syncthreads();               // S4: q3 staged, B0 free
    stageQ(B0, 0);                 // P-stage0 flies under q3 MFMAs
    mfmaA(B1, 3);

    // ---- softmax partials over this wave's 64 cols ----
    float sqv[4];
#pragma unroll
    for (int nf = 0; nf < 4; nf++) sqv[nf] = sq[b * J_ + (ch << 6) + (nf << 4) + lr];
    float mp[4], sp[4];
#pragma unroll
    for (int r = 0; r < 4; r++) {
        float m = -1e30f;
#pragma unroll
        for (int nf = 0; nf < 4; nf++) { acc[nf][r] += sqv[nf]; m = fmaxf(m, acc[nf][r]); }
#pragma unroll
        for (int msk = 8; msk >= 1; msk >>= 1) m = fmaxf(m, __shfl_xor(m, msk));
        float s = 0.f;
#pragma unroll
        for (int nf = 0; nf < 4; nf++) { float e = __expf(acc[nf][r] - m); acc[nf][r] = e; s += e; }
#pragma unroll
        for (int msk = 8; msk >= 1; msk >>= 1) s += __shfl_xor(s, msk);
        mp[r] = m; sp[r] = s;
    }
    __syncthreads();               // S5: B1 free (all waves done with mfmaA(B1,3))
    if (lr == 0) {
#pragma unroll
        for (int r = 0; r < 4; r++) {
            int row = R0 + (lq << 2) + r;
            sc[(row << 2) + (ch << 1)] = mp[r];
            sc[(row << 2) + (ch << 1) + 1] = sp[r];
        }
    }
    __syncthreads();               // S5b: sc visible

    // ---- merge halves, write P (bf16 swizzled); keep merged maxes in regs ----
    float mm[4];
#pragma unroll
    for (int r = 0; r < 4; r++) {
        int row = R0 + (lq << 2) + r;
        float m0 = sc[(row << 2)],     s0 = sc[(row << 2) + 1];
        float m1 = sc[(row << 2) + 2], s1 = sc[(row << 2) + 3];
        float m = fmaxf(m0, m1);
        float sum = s0 * __expf(m0 - m) + s1 * __expf(m1 - m);
        float scale = __expf(mp[r] - m) / sum;
#pragma unroll
        for (int nf = 0; nf < 4; nf++) {
            int cc = (ch << 6) + (nf << 4) + lr;
            int chunk = cc >> 3;
            *(unsigned short*)(Ps + row * 256 + ((chunk ^ (row & 7)) << 4) + ((lr & 7) << 1)) =
                f2bf(acc[nf][r] * scale);
        }
        mm[r] = m;
    }
    __syncthreads();               // S6: Ps visible, sc consumed -> B1 reusable
    stageQ(B1, 1);                 // stage1 flies under first PV MFMAs

    // ---- phase B: P(32x128) . qT(256x128)^T, 4 stages ----
    int prow = R0 + lr;
    s8v pf[4];
#pragma unroll
    for (int jk = 0; jk < 4; jk++)
        pf[jk] = *(const s8v*)(Ps + prow * 256 + ((((jk << 2) + lq) ^ (prow & 7)) << 4));

    f4 acc2[8];
#pragma unroll
    for (int ai = 0; ai < 8; ai++) acc2[ai] = (f4){0.f, 0.f, 0.f, 0.f};

    auto mfmaB = [&](char* rb, int s) {
#pragma unroll
        for (int df2 = 0; df2 < 2; df2++) {
            int dr = (ch << 5) + (df2 << 4) + lr;
            int ai = (s << 1) + df2;
#pragma unroll
            for (int jk = 0; jk < 4; jk++) {
                s8v bv = *(const s8v*)(rb + (dr << 8) + ((((jk << 2) + lq) ^ (dr & 7)) << 4));
                acc2[ai] = __builtin_amdgcn_mfma_f32_16x16x32_bf16(pf[jk], bv, acc2[ai], 0, 0, 0);
            }
        }
    };

    mfmaB(B0, 0);
    __syncthreads();               // S7: B0 free
    stageQ(B0, 2);
    mfmaB(B1, 1);
    __syncthreads();               // S8: B1 free, stage2 staged
    stageQ(B1, 3);
    mfmaB(B0, 2);
    __syncthreads();               // S9: stage3 staged
    mfmaB(B1, 3);
    __syncthreads();               // S10: bufs free for epilogue

    // ---- epilogue: acc2 -> LDS (swizzled) -> f4-coalesced nt-stores of q1,q2,q3 ----
    float* cq = (float*)lds;       // 32 rows x 256 cols fp32 = 32 KB
#pragma unroll
    for (int s2 = 0; s2 < 4; s2++)
#pragma unroll
        for (int df2 = 0; df2 < 2; df2++) {
            int col = (s2 << 6) + (ch << 5) + (df2 << 4) + lr;
            int ai = (s2 << 1) + df2;
            int chunk = col >> 2;
#pragma unroll
            for (int r = 0; r < 4; r++) {
                int row = R0 + (lq << 2) + r;
                *(float*)((char*)cq + (row << 10) + ((chunk ^ (row & 7)) << 4) + ((col & 3) << 2)) = acc2[ai][r];
            }
        }
    __syncthreads();               // S11

    {
        int row = tid >> 3;                   // 0..31
        int o = b * T_ + t0 + row;
        const float* crow = ctx + o * D_;
        float* orow = out + o * 1024;
#pragma unroll
        for (int i = 0; i < 8; i++) {
            int col4 = (i << 5) + ((tid & 7) << 2);
            int chunk = col4 >> 2;
            f4 val = *(const f4*)((char*)cq + (row << 10) + ((chunk ^ (row & 7)) << 4));
            f4 cx = *(const f4*)(crow + col4);
            f4 v3 = cx * val;
            __builtin_nontemporal_store(cx, (f4*)(orow + col4));
            __builtin_nontemporal_store(val, (f4*)(orow + 256 + col4));
            __builtin_nontemporal_store(v3, (f4*)(orow + 512 + col4));
        }
    }

    // ---- q2c partial: wave (rg,ch) covers rows rg*16..+15, d = ch*128 + l*2 (+0,1) ----
    {
        float m16[16];
#pragma unroll
        for (int i = 0; i < 16; i++) m16[i] = __shfl(mm[i & 3], (i >> 2) << 4);
        float mw = -1e30f;
#pragma unroll
        for (int i = 0; i < 16; i++) mw = fmaxf(mw, m16[i]);
        const float* cp = ctx + (b * T_ + t0 + R0) * D_ + (ch << 7) + (l << 1);
        f2 p = (f2){0.f, 0.f};
        float sw_ = 0.f;
#pragma unroll 4
        for (int t = 0; t < 16; t++) {
            float e = __expf(m16[t] - mw);
            sw_ += e;
            f2 cv = *(const f2*)(cp + t * D_);
            p.x += e * cv.x; p.y += e * cv.y;
        }
        int pidx = (bid << 1) | rg;
        *(f2*)(pq2c + (pidx << 8) + (ch << 7) + (l << 1)) = p;
        if (ch == 0 && l == 0) { pms[pidx * 2] = mw; pms[pidx * 2 + 1] = sw_; }
    }

    // ======== per-batch sync (device-scope counter), merge by leader, then quarter 4 ========
    __threadfence();
    __syncthreads();
    unsigned int* cnt  = ctrl;
    unsigned int* done = ctrl + 32;
    if (tid == 0) __hip_atomic_fetch_add(&cnt[b], 1u, __ATOMIC_RELEASE, __HIP_MEMORY_SCOPE_AGENT);

    float* q2s = (float*)lds;      // 1 KB (cq consumed above; guarded by syncthreads below)
    if (tc == 0) {
        if (tid == 0) {
            while (__hip_atomic_load(&cnt[b], __ATOMIC_ACQUIRE, __HIP_MEMORY_SCOPE_AGENT) < 32u)
                __builtin_amdgcn_s_sleep(8);
        }
        __syncthreads();
        __threadfence();
        const float* pm = pms + b * 128;
        float mx = -1e30f;
#pragma unroll 8
        for (int i = 0; i < 64; i++) mx = fmaxf(mx, pm[2 * i]);
        float sm = 0.f, q2 = 0.f;
#pragma unroll 4
        for (int i = 0; i < 64; i++) {
            float e = __expf(pm[2 * i] - mx);
            sm += pm[2 * i + 1] * e;
            q2 += e * pq2c[((b << 6) + i) * 256 + tid];
        }
        q2 /= sm;
        q2cf[b * 256 + tid] = q2;
        __threadfence();
        __syncthreads();           // all 256 q2cf stores done before flag
        if (tid == 0) __hip_atomic_store(&done[b], 1u, __ATOMIC_RELEASE, __HIP_MEMORY_SCOPE_AGENT);
        q2s[tid] = q2;
    } else {
        if (tid == 0) {
            while (__hip_atomic_load(&done[b], __ATOMIC_ACQUIRE, __HIP_MEMORY_SCOPE_AGENT) == 0u)
                __builtin_amdgcn_s_sleep(8);
        }
        __syncthreads();
        __threadfence();
        q2s[tid] = q2cf[b * 256 + tid];
    }
    __syncthreads();

    {
        int row = tid >> 3;
        int o = b * T_ + t0 + row;
        const float* crow = ctx + o * D_;
        float* orow = out + o * 1024;
#pragma unroll
        for (int i = 0; i < 8; i++) {
            int col4 = (i << 5) + ((tid & 7) << 2);
            f4 cx = *(const f4*)(crow + col4);
            f4 qv = *(const f4*)&q2s[col4];
            f4 r = cx * qv;
            __builtin_nontemporal_store(r, (f4*)(orow + 768 + col4));
        }
    }
}

extern "C" void kernel_launch(void* const* d_in, const int* in_sizes, int n_in,
                              void* d_out, int out_size, void* d_ws, size_t ws_size,
                              hipStream_t stream) {
    const float* ctx   = (const float*)d_in[0];
    const float* query = (const float*)d_in[1];
    const float* w     = (const float*)d_in[2];
    float* out = (float*)d_out;

    unsigned short* Bqh = (unsigned short*)d_ws;        // 2 MB
    unsigned short* qTh = Bqh + B_ * J_ * D_;           // 2 MB
    float* fws = (float*)(qTh + B_ * J_ * D_);
    float* sq   = fws;                                  // 4096 floats
    float* pq2c = fws + 4096;                           // 2048*256 floats (2 MB)
    float* pms  = fws + 4096 + 2048 * 256;              // 4096 floats
    float* q2cf = pms + 4096;                           // 8192 floats
    unsigned int* ctrl = (unsigned int*)(q2cf + 8192);  // cnt[32] + done[32]

    k_pre<<<B_ * 8, 256, 0, stream>>>(query, w, Bqh, sq, qTh, ctrl);
    k_main<<<B_ * (T_ / 32), 256, 0, stream>>>(ctx, Bqh, qTh, sq, pq2c, pms, q2cf, ctrl, out);
}

// Round 12
// 77.027 us; speedup vs baseline: 6.3289x; 6.3289x over previous
//
#include <hip/hip_runtime.h>

typedef float f4 __attribute__((ext_vector_type(4)));
typedef float f2 __attribute__((ext_vector_type(2)));
typedef short s8v __attribute__((ext_vector_type(8)));        // 8 bf16
typedef unsigned int u2v __attribute__((ext_vector_type(2)));
typedef unsigned int u4v __attribute__((ext_vector_type(4)));

#define B_ 32
#define T_ 1024
#define J_ 128
#define D_ 256

__device__ inline unsigned short f2bf(float x) {
    unsigned int u = __float_as_uint(x);
    u += 0x7fffu + ((u >> 16) & 1u);      // RNE
    return (unsigned short)(u >> 16);
}

__device__ __forceinline__ void ldsload16(const void* g, void* l) {
    __builtin_amdgcn_global_load_lds(
        (const __attribute__((address_space(1))) void*)g,
        (__attribute__((address_space(3))) void*)l, 16, 0, 0);
}

// ---------------- K_pre: fused Bqh = bf16(w3*q+w1), sq = q.w2, qTh = bf16 transpose ----------------
__global__ __launch_bounds__(256) void k_pre(const float* __restrict__ q, const float* __restrict__ w,
                                             unsigned short* __restrict__ Bqh, float* __restrict__ sq,
                                             unsigned short* __restrict__ qTh) {
    __shared__ float t_[16][260];
    int b = blockIdx.x >> 3, jt = blockIdx.x & 7;
    int tid = threadIdx.x;
    const float* qb = q + (b * J_ + jt * 16) * D_;

#pragma unroll
    for (int k = 0; k < 4; k++) {
        int idx = tid + (k << 8);              // f4 id over 16x64
        int jj = idx >> 6, d4 = idx & 63;
        f4 v = *(const f4*)(qb + jj * D_ + (d4 << 2));
        *(f4*)&t_[jj][d4 << 2] = v;
        f4 w1v = *(const f4*)(w + (d4 << 2));
        f4 w3v = *(const f4*)(w + 2 * D_ + (d4 << 2));
        u2v p;
        p[0] = (unsigned int)f2bf(w3v[0] * v[0] + w1v[0]) | ((unsigned int)f2bf(w3v[1] * v[1] + w1v[1]) << 16);
        p[1] = (unsigned int)f2bf(w3v[2] * v[2] + w1v[2]) | ((unsigned int)f2bf(w3v[3] * v[3] + w1v[3]) << 16);
        *(u2v*)(Bqh + (b * J_ + jt * 16 + jj) * D_ + (d4 << 2)) = p;
    }
    __syncthreads();

    // sq: 16 threads per j row
    {
        int jj = tid >> 4, dg = tid & 15;
        float p = 0.f;
#pragma unroll
        for (int i = 0; i < 16; i++) {
            int d = (dg << 4) + i;
            p += t_[jj][d] * w[D_ + d];
        }
#pragma unroll
        for (int m = 8; m >= 1; m >>= 1) p += __shfl_xor(p, m);
        if (dg == 0) sq[b * J_ + jt * 16 + jj] = p;
    }

    // qT: thread = d; write 16 j's (32 B) as two u4v
    {
        int dd = tid;
        unsigned int pk[8];
#pragma unroll
        for (int i = 0; i < 8; i++) {
            pk[i] = (unsigned int)f2bf(t_[2 * i][dd]) | ((unsigned int)f2bf(t_[2 * i + 1][dd]) << 16);
        }
        u4v v0, v1;
        v0[0] = pk[0]; v0[1] = pk[1]; v0[2] = pk[2]; v0[3] = pk[3];
        v1[0] = pk[4]; v1[1] = pk[5]; v1[2] = pk[6]; v1[3] = pk[7];
        unsigned short* dst = qTh + (b * D_ + dd) * J_ + jt * 16;
        *(u4v*)dst = v0;
        *(u4v*)(dst + 8) = v1;
    }
}

// ---------------- K2: 6-blocks/CU, 8KB-staged MFMA S -> softmax -> MFMA PV -> q1,q2,q3 + partials ----------------
__global__ __launch_bounds__(256, 6) void k_main(const float* __restrict__ ctx,
                                                 const unsigned short* __restrict__ Bqh,
                                                 const unsigned short* __restrict__ qTh,
                                                 const float* __restrict__ sq,
                                                 float* __restrict__ pq2c, float* __restrict__ pms,
                                                 float* __restrict__ out) {
    __shared__ __align__(16) char lds[25088];
    char* B0 = lds;                     // 8 KB
    char* B1 = lds + 8192;              // 8 KB
    char* Ps = lds + 16384;             // 8 KB: P 32x128 bf16, swizzled
    float* sc = (float*)(lds + 24576);  // 512 B softmax scratch

    int bid = blockIdx.x;
    int b  = bid >> 5;                  // contiguous: each XCD's live set = one batch's Bq+qT (4 MB, fits L2)
    int tc = bid & 31;
    int t0 = tc << 5;
    int tid = threadIdx.x;
    int w = tid >> 6, l = tid & 63, lr = l & 15, lq = l >> 4;
    int rg = w & 1, ch = w >> 1;
    int R0 = rg << 4;

    const unsigned short* BqB  = Bqh + b * J_ * D_;
    const unsigned short* qThB = qTh + b * D_ * J_;

    // stage A: 8 KB = [64 line][8 slot16] line-pair layout; stage sa = 32-d block
    auto stageA = [&](char* buf, int sa) {
#pragma unroll
        for (int i = 0; i < 2; i++) {
            int g = tid + (i << 8);               // 0..511
            int line = g >> 3, s8 = g & 7;
            int L = s8 ^ (line & 7);
            int jr = (line << 1) | (L >> 2);
            ldsload16(BqB + jr * D_ + sa * 32 + ((L & 3) << 3), buf + (g << 4));
        }
    };
    // stage B: 8 KB = [32 d][16 slot16]; stage sb = 32-d block of qT
    auto stageQ = [&](char* buf, int sb) {
#pragma unroll
        for (int i = 0; i < 2; i++) {
            int g = tid + (i << 8);
            int dr = g >> 4, c = g & 15;
            ldsload16(qThB + (sb * 32 + dr) * J_ + ((c ^ (dr & 7)) << 3), buf + (g << 4));
        }
    };

    f4 acc[4];
#pragma unroll
    for (int nf = 0; nf < 4; nf++) acc[nf] = (f4){0.f, 0.f, 0.f, 0.f};

    stageA(B0, 0);
    stageA(B1, 1);

    // sq (hoisted for latency)
    float sqv[4];
#pragma unroll
    for (int nf = 0; nf < 4; nf++) sqv[nf] = sq[b * J_ + (ch << 6) + (nf << 4) + lr];

    // ctx rows -> bf16 A-frags
    const float* ctxA = ctx + (b * T_ + t0 + R0 + lr) * D_;
    s8v af[8];
#pragma unroll
    for (int k = 0; k < 8; k++) {
        f4 a0 = *(const f4*)(ctxA + k * 32 + lq * 8);
        f4 a1 = *(const f4*)(ctxA + k * 32 + lq * 8 + 4);
        union { unsigned short u[8]; s8v v; } t;
#pragma unroll
        for (int e = 0; e < 4; e++) { t.u[e] = f2bf(a0[e]); t.u[e + 4] = f2bf(a1[e]); }
        af[k] = t.v;
    }

    auto mfmaA = [&](char* buf, int sa) {
#pragma unroll
        for (int nf = 0; nf < 4; nf++) {
            int jr = (ch << 6) + (nf << 4) + lr;
            int line = jr >> 1;
            int slot = (((jr & 1) << 2) | lq) ^ (line & 7);
            s8v bv = *(const s8v*)(buf + (line << 7) + (slot << 4));
            acc[nf] = __builtin_amdgcn_mfma_f32_16x16x32_bf16(af[sa], bv, acc[nf], 0, 0, 0);
        }
    };

    __syncthreads();                              // stages 0,1 visible
    mfmaA(B0, 0);
    __syncthreads(); stageA(B0, 2); mfmaA(B1, 1);
    __syncthreads(); stageA(B1, 3); mfmaA(B0, 2);
    __syncthreads(); stageA(B0, 4); mfmaA(B1, 3);
    __syncthreads(); stageA(B1, 5); mfmaA(B0, 4);
    __syncthreads(); stageA(B0, 6); mfmaA(B1, 5);
    __syncthreads(); stageA(B1, 7); mfmaA(B0, 6);
    __syncthreads(); mfmaA(B1, 7);

    // ---- softmax partials over this wave's 64 cols ----
    float mp[4], sp[4];
#pragma unroll
    for (int r = 0; r < 4; r++) {
        float m = -1e30f;
#pragma unroll
        for (int nf = 0; nf < 4; nf++) { acc[nf][r] += sqv[nf]; m = fmaxf(m, acc[nf][r]); }
#pragma unroll
        for (int msk = 8; msk >= 1; msk >>= 1) m = fmaxf(m, __shfl_xor(m, msk));
        float s = 0.f;
#pragma unroll
        for (int nf = 0; nf < 4; nf++) { float e = __expf(acc[nf][r] - m); acc[nf][r] = e; s += e; }
#pragma unroll
        for (int msk = 8; msk >= 1; msk >>= 1) s += __shfl_xor(s, msk);
        mp[r] = m; sp[r] = s;
    }
    if (lr == 0) {
#pragma unroll
        for (int r = 0; r < 4; r++) {
            int row = R0 + (lq << 2) + r;
            sc[(row << 2) + (ch << 1)] = mp[r];
            sc[(row << 2) + (ch << 1) + 1] = sp[r];
        }
    }
    __syncthreads();               // sc visible; B0,B1 free
    stageQ(B0, 0);                 // deep prefetch under merge
    stageQ(B1, 1);

    // ---- merge halves, write P (bf16 swizzled); keep merged maxes in regs ----
    float mm[4];
#pragma unroll
    for (int r = 0; r < 4; r++) {
        int row = R0 + (lq << 2) + r;
        float m0 = sc[(row << 2)],     s0 = sc[(row << 2) + 1];
        float m1 = sc[(row << 2) + 2], s1 = sc[(row << 2) + 3];
        float m = fmaxf(m0, m1);
        float sum = s0 * __expf(m0 - m) + s1 * __expf(m1 - m);
        float scale = __expf(mp[r] - m) / sum;
#pragma unroll
        for (int nf = 0; nf < 4; nf++) {
            int cc = (ch << 6) + (nf << 4) + lr;
            int chunk = cc >> 3;
            *(unsigned short*)(Ps + row * 256 + ((chunk ^ (row & 7)) << 4) + ((lr & 7) << 1)) =
                f2bf(acc[nf][r] * scale);
        }
        mm[r] = m;
    }
    __syncthreads();               // Ps visible + stages 0,1 landed

    // ---- phase B: P(32x128) . qT(256x128)^T, 8 stages of 32 d-rows ----
    int prow = R0 + lr;
    s8v pf[4];
#pragma unroll
    for (int jk = 0; jk < 4; jk++)
        pf[jk] = *(const s8v*)(Ps + prow * 256 + ((((jk << 2) + lq) ^ (prow & 7)) << 4));

    f4 acc2[8];
#pragma unroll
    for (int ai = 0; ai < 8; ai++) acc2[ai] = (f4){0.f, 0.f, 0.f, 0.f};

    int drB = (ch << 4) + lr;      // wave's d-row within each 32-row stage
    auto mfmaB = [&](char* rb, int sb) {
#pragma unroll
        for (int jk = 0; jk < 4; jk++) {
            s8v bv = *(const s8v*)(rb + (drB << 8) + ((((jk << 2) | lq) ^ (drB & 7)) << 4));
            acc2[sb] = __builtin_amdgcn_mfma_f32_16x16x32_bf16(pf[jk], bv, acc2[sb], 0, 0, 0);
        }
    };

    mfmaB(B0, 0);
    __syncthreads(); stageQ(B0, 2); mfmaB(B1, 1);
    __syncthreads(); stageQ(B1, 3); mfmaB(B0, 2);
    __syncthreads(); stageQ(B0, 4); mfmaB(B1, 3);
    __syncthreads(); stageQ(B1, 5); mfmaB(B0, 4);
    __syncthreads(); stageQ(B0, 6); mfmaB(B1, 5);
    __syncthreads(); stageQ(B1, 7); mfmaB(B0, 6);
    __syncthreads(); mfmaB(B1, 7);
    __syncthreads();               // all stage bufs free for epilogue

    // ---- epilogue: two 16-row passes through cq (16 KB = B0|B1) ----
    float* cq = (float*)lds;
#pragma unroll
    for (int p = 0; p < 2; p++) {
        if (rg == p) {
#pragma unroll
            for (int sb = 0; sb < 8; sb++) {
                int col = (sb << 5) + (ch << 4) + lr;
                int chunk = col >> 2;
#pragma unroll
                for (int r = 0; r < 4; r++) {
                    int lrow = (lq << 2) + r;
                    *(float*)((char*)cq + (lrow << 10) + ((chunk ^ (lrow & 7)) << 4) + ((col & 3) << 2)) = acc2[sb][r];
                }
            }
        }
        __syncthreads();
        {
            int lrow = tid >> 4;               // 0..15
            int o = b * T_ + t0 + (p << 4) + lrow;
            const float* crow = ctx + o * D_;
            float* orow = out + o * 1024;
#pragma unroll
            for (int i = 0; i < 4; i++) {
                int col4 = (i << 6) + ((tid & 15) << 2);
                int chunk = col4 >> 2;
                f4 val = *(const f4*)((char*)cq + (lrow << 10) + ((chunk ^ (lrow & 7)) << 4));
                f4 cx = *(const f4*)(crow + col4);
                f4 v3 = cx * val;
                __builtin_nontemporal_store(cx, (f4*)(orow + col4));
                __builtin_nontemporal_store(val, (f4*)(orow + 256 + col4));
                __builtin_nontemporal_store(v3, (f4*)(orow + 512 + col4));
            }
        }
        __syncthreads();
    }

    // ---- q2c partial: wave (rg,ch) covers rows rg*16..+15, d = ch*128 + l*2 (+0,1) ----
    {
        float m16[16];
#pragma unroll
        for (int i = 0; i < 16; i++) m16[i] = __shfl(mm[i & 3], (i >> 2) << 4);
        float mw = -1e30f;
#pragma unroll
        for (int i = 0; i < 16; i++) mw = fmaxf(mw, m16[i]);
        const float* cp = ctx + (b * T_ + t0 + R0) * D_ + (ch << 7) + (l << 1);
        f2 p = (f2){0.f, 0.f};
        float sw_ = 0.f;
#pragma unroll 4
        for (int t = 0; t < 16; t++) {
            float e = __expf(m16[t] - mw);
            sw_ += e;
            f2 cv = *(const f2*)(cp + t * D_);
            p.x += e * cv.x; p.y += e * cv.y;
        }
        int pidx = (bid << 1) | rg;
        *(f2*)(pq2c + (pidx << 8) + (ch << 7) + (l << 1)) = p;
        if (ch == 0 && l == 0) { pms[pidx * 2] = mw; pms[pidx * 2 + 1] = sw_; }
    }
}

// ---------------- K_tail: merge 64 partials -> q2c; write quarter 4 ----------------
__global__ __launch_bounds__(256) void k_tail(const float* __restrict__ ctx,
                                              const float* __restrict__ pq2c, const float* __restrict__ pms,
                                              float* __restrict__ out) {
    int b = blockIdx.x >> 5, tc = blockIdx.x & 31;
    int tid = threadIdx.x;
    const float* pm = pms + b * 128;

    float mx = -1e30f;
#pragma unroll 8
    for (int i = 0; i < 64; i++) mx = fmaxf(mx, pm[2 * i]);
    float sm = 0.f, q2 = 0.f;
#pragma unroll 4
    for (int i = 0; i < 64; i++) {
        float e = __expf(pm[2 * i] - mx);
        sm += pm[2 * i + 1] * e;
        q2 += e * pq2c[((b << 6) + i) * 256 + tid];
    }
    q2 /= sm;
    __shared__ float q2s[256];
    q2s[tid] = q2;
    __syncthreads();

    int row = tid >> 3;
    int o = b * T_ + tc * 32 + row;
    const float* crow = ctx + o * D_;
    float* orow = out + o * 1024;
#pragma unroll
    for (int i = 0; i < 8; i++) {
        int col4 = (i << 5) + ((tid & 7) << 2);
        f4 cx = *(const f4*)(crow + col4);
        f4 qv = *(const f4*)&q2s[col4];
        f4 r = cx * qv;
        __builtin_nontemporal_store(r, (f4*)(orow + 768 + col4));
    }
}

extern "C" void kernel_launch(void* const* d_in, const int* in_sizes, int n_in,
                              void* d_out, int out_size, void* d_ws, size_t ws_size,
                              hipStream_t stream) {
    const float* ctx   = (const float*)d_in[0];
    const float* query = (const float*)d_in[1];
    const float* w     = (const float*)d_in[2];
    float* out = (float*)d_out;

    unsigned short* Bqh = (unsigned short*)d_ws;        // 2 MB
    unsigned short* qTh = Bqh + B_ * J_ * D_;           // 2 MB
    float* fws = (float*)(qTh + B_ * J_ * D_);
    float* sq   = fws;                                  // 4096 floats
    float* pq2c = fws + 4096;                           // 2048*256 floats (2 MB)
    float* pms  = fws + 4096 + 2048 * 256;              // 4096 floats

    k_pre<<<B_ * 8, 256, 0, stream>>>(query, w, Bqh, sq, qTh);
    k_main<<<B_ * (T_ / 32), 256, 0, stream>>>(ctx, Bqh, qTh, sq, pq2c, pms, out);
    k_tail<<<B_ * 32, 256, 0, stream>>>(ctx, pq2c, pms, out);
}

// Round 13
// 73.508 us; speedup vs baseline: 6.6319x; 1.0479x over previous
//
#include <hip/hip_runtime.h>

typedef float f4 __attribute__((ext_vector_type(4)));
typedef float f2 __attribute__((ext_vector_type(2)));
typedef short s8v __attribute__((ext_vector_type(8)));        // 8 bf16
typedef unsigned int u2v __attribute__((ext_vector_type(2)));
typedef unsigned int u4v __attribute__((ext_vector_type(4)));

#define B_ 32
#define T_ 1024
#define J_ 128
#define D_ 256

__device__ inline unsigned short f2bf(float x) {
    unsigned int u = __float_as_uint(x);
    u += 0x7fffu + ((u >> 16) & 1u);      // RNE
    return (unsigned short)(u >> 16);
}

__device__ __forceinline__ void ldsload16(const void* g, void* l) {
    __builtin_amdgcn_global_load_lds(
        (const __attribute__((address_space(1))) void*)g,
        (__attribute__((address_space(3))) void*)l, 16, 0, 0);
}

// ---------------- K_pre: fused Bqh = bf16(w3*q+w1), sq = q.w2, qTh = bf16 transpose ----------------
__global__ __launch_bounds__(256) void k_pre(const float* __restrict__ q, const float* __restrict__ w,
                                             unsigned short* __restrict__ Bqh, float* __restrict__ sq,
                                             unsigned short* __restrict__ qTh) {
    __shared__ float t_[16][260];
    int b = blockIdx.x >> 3, jt = blockIdx.x & 7;
    int tid = threadIdx.x;
    const float* qb = q + (b * J_ + jt * 16) * D_;

#pragma unroll
    for (int k = 0; k < 4; k++) {
        int idx = tid + (k << 8);              // f4 id over 16x64
        int jj = idx >> 6, d4 = idx & 63;
        f4 v = *(const f4*)(qb + jj * D_ + (d4 << 2));
        *(f4*)&t_[jj][d4 << 2] = v;
        f4 w1v = *(const f4*)(w + (d4 << 2));
        f4 w3v = *(const f4*)(w + 2 * D_ + (d4 << 2));
        u2v p;
        p[0] = (unsigned int)f2bf(w3v[0] * v[0] + w1v[0]) | ((unsigned int)f2bf(w3v[1] * v[1] + w1v[1]) << 16);
        p[1] = (unsigned int)f2bf(w3v[2] * v[2] + w1v[2]) | ((unsigned int)f2bf(w3v[3] * v[3] + w1v[3]) << 16);
        *(u2v*)(Bqh + (b * J_ + jt * 16 + jj) * D_ + (d4 << 2)) = p;
    }
    __syncthreads();

    {
        int jj = tid >> 4, dg = tid & 15;
        float p = 0.f;
#pragma unroll
        for (int i = 0; i < 16; i++) {
            int d = (dg << 4) + i;
            p += t_[jj][d] * w[D_ + d];
        }
#pragma unroll
        for (int m = 8; m >= 1; m >>= 1) p += __shfl_xor(p, m);
        if (dg == 0) sq[b * J_ + jt * 16 + jj] = p;
    }

    {
        int dd = tid;
        unsigned int pk[8];
#pragma unroll
        for (int i = 0; i < 8; i++) {
            pk[i] = (unsigned int)f2bf(t_[2 * i][dd]) | ((unsigned int)f2bf(t_[2 * i + 1][dd]) << 16);
        }
        u4v v0, v1;
        v0[0] = pk[0]; v0[1] = pk[1]; v0[2] = pk[2]; v0[3] = pk[3];
        v1[0] = pk[4]; v1[1] = pk[5]; v1[2] = pk[6]; v1[3] = pk[7];
        unsigned short* dst = qTh + (b * D_ + dd) * J_ + jt * 16;
        *(u4v*)dst = v0;
        *(u4v*)(dst + 8) = v1;
    }
}

// ---------------- K2: 64-row tile (2 row-groups share staged tiles) ----------------
__global__ __launch_bounds__(256, 3) void k_main(const float* __restrict__ ctx,
                                                 const unsigned short* __restrict__ Bqh,
                                                 const unsigned short* __restrict__ qTh,
                                                 const float* __restrict__ sq,
                                                 float* __restrict__ pq2c, float* __restrict__ pms,
                                                 float* __restrict__ out) {
    __shared__ __align__(16) char lds[40960];
    char* B0 = lds;                     // 16 KB
    char* B1 = lds + 16384;             // 16 KB
    char* Ps = lds + 32768;             // 8 KB: P group0, swizzled
    float* sc = (float*)B1;             // 1 KB overlay (64 rows): live S5..S6
    char* PB = B1 + 1024;               // 8 KB overlay: P group1, live S5b..S6b

    int bid = blockIdx.x;               // 0..511
    int b  = ((bid & 7) << 2) | ((bid >> 3) & 3);   // same-batch blocks share an XCD
    int tt = bid >> 5;                  // 0..15 (64-row tile)
    int t0 = tt << 6;
    int tid = threadIdx.x;
    int w = tid >> 6, l = tid & 63, lr = l & 15, lq = l >> 4;
    int rg = w & 1, ch = w >> 1;
    int R0 = rg << 4;

    const unsigned short* BqB  = Bqh + b * J_ * D_;
    const unsigned short* qThB = qTh + b * D_ * J_;

    auto stageBq = [&](char* buf, int qt) {
#pragma unroll
        for (int i = 0; i < 4; i++) {
            int g = tid + (i << 8);
            int jr = g >> 3, c = g & 7;
            ldsload16(BqB + jr * D_ + (qt << 6) + ((c ^ (jr & 7)) << 3),
                      buf + (i << 12) + (w << 10));
        }
    };
    auto stageQ = [&](char* buf, int st) {
#pragma unroll
        for (int i = 0; i < 4; i++) {
            int g = tid + (i << 8);
            int dr = g >> 4, c = g & 15;
            ldsload16(qThB + ((st << 6) + dr) * J_ + ((c ^ (dr & 7)) << 3),
                      buf + (i << 12) + (w << 10));
        }
    };

    f4 acc0[4], acc1[4];
#pragma unroll
    for (int nf = 0; nf < 4; nf++) { acc0[nf] = (f4){0.f,0.f,0.f,0.f}; acc1[nf] = (f4){0.f,0.f,0.f,0.f}; }

    stageBq(B0, 0);
    stageBq(B1, 1);

    // ctx rows -> bf16 A-frags, both row-groups
    const float* ctxA0 = ctx + (b * T_ + t0 + R0 + lr) * D_;
    const float* ctxA1 = ctxA0 + 32 * D_;
    s8v af0[8], af1[8];
#pragma unroll
    for (int k = 0; k < 8; k++) {
        f4 a0 = *(const f4*)(ctxA0 + k * 32 + lq * 8);
        f4 a1 = *(const f4*)(ctxA0 + k * 32 + lq * 8 + 4);
        union { unsigned short u[8]; s8v v; } t;
#pragma unroll
        for (int e = 0; e < 4; e++) { t.u[e] = f2bf(a0[e]); t.u[e + 4] = f2bf(a1[e]); }
        af0[k] = t.v;
    }
#pragma unroll
    for (int k = 0; k < 8; k++) {
        f4 a0 = *(const f4*)(ctxA1 + k * 32 + lq * 8);
        f4 a1 = *(const f4*)(ctxA1 + k * 32 + lq * 8 + 4);
        union { unsigned short u[8]; s8v v; } t;
#pragma unroll
        for (int e = 0; e < 4; e++) { t.u[e] = f2bf(a0[e]); t.u[e + 4] = f2bf(a1[e]); }
        af1[k] = t.v;
    }

    auto mfmaA2 = [&](char* buf, int qt) {
#pragma unroll
        for (int kk = 0; kk < 2; kk++)
#pragma unroll
            for (int nf = 0; nf < 4; nf++) {
                int jr = (ch << 6) + (nf << 4) + lr;
                s8v bv = *(const s8v*)(buf + (jr << 7) + ((((kk << 2) | lq) ^ (jr & 7)) << 4));
                acc0[nf] = __builtin_amdgcn_mfma_f32_16x16x32_bf16(af0[(qt << 1) | kk], bv, acc0[nf], 0, 0, 0);
                acc1[nf] = __builtin_amdgcn_mfma_f32_16x16x32_bf16(af1[(qt << 1) | kk], bv, acc1[nf], 0, 0, 0);
            }
    };

    __syncthreads();               // S1
    mfmaA2(B0, 0);
    __syncthreads();               // S2
    stageBq(B0, 2);
    mfmaA2(B1, 1);
    __syncthreads();               // S3
    stageBq(B1, 3);
    mfmaA2(B0, 2);
    __syncthreads();               // S4
    stageQ(B0, 0);
    mfmaA2(B1, 3);

    // ---- softmax partials, both groups ----
    float sqv[4];
#pragma unroll
    for (int nf = 0; nf < 4; nf++) sqv[nf] = sq[b * J_ + (ch << 6) + (nf << 4) + lr];
    float mp0[4], sp0[4], mp1[4], sp1[4];
#pragma unroll
    for (int r = 0; r < 4; r++) {
        float m = -1e30f;
#pragma unroll
        for (int nf = 0; nf < 4; nf++) { acc0[nf][r] += sqv[nf]; m = fmaxf(m, acc0[nf][r]); }
#pragma unroll
        for (int msk = 8; msk >= 1; msk >>= 1) m = fmaxf(m, __shfl_xor(m, msk));
        float s = 0.f;
#pragma unroll
        for (int nf = 0; nf < 4; nf++) { float e = __expf(acc0[nf][r] - m); acc0[nf][r] = e; s += e; }
#pragma unroll
        for (int msk = 8; msk >= 1; msk >>= 1) s += __shfl_xor(s, msk);
        mp0[r] = m; sp0[r] = s;
    }
#pragma unroll
    for (int r = 0; r < 4; r++) {
        float m = -1e30f;
#pragma unroll
        for (int nf = 0; nf < 4; nf++) { acc1[nf][r] += sqv[nf]; m = fmaxf(m, acc1[nf][r]); }
#pragma unroll
        for (int msk = 8; msk >= 1; msk >>= 1) m = fmaxf(m, __shfl_xor(m, msk));
        float s = 0.f;
#pragma unroll
        for (int nf = 0; nf < 4; nf++) { float e = __expf(acc1[nf][r] - m); acc1[nf][r] = e; s += e; }
#pragma unroll
        for (int msk = 8; msk >= 1; msk >>= 1) s += __shfl_xor(s, msk);
        mp1[r] = m; sp1[r] = s;
    }
    __syncthreads();               // S5: B1 free (mfmaA2(B1,3) consumed)
    if (lr == 0) {
#pragma unroll
        for (int r = 0; r < 4; r++) {
            int row = R0 + (lq << 2) + r;
            sc[(row << 2) + (ch << 1)] = mp0[r];
            sc[(row << 2) + (ch << 1) + 1] = sp0[r];
            sc[((32 + row) << 2) + (ch << 1)] = mp1[r];
            sc[((32 + row) << 2) + (ch << 1) + 1] = sp1[r];
        }
    }
    __syncthreads();               // S5b: sc visible

    // ---- merge + write P (group0 -> Ps, group1 -> PB) ----
    float mm0[4], mm1[4];
#pragma unroll
    for (int r = 0; r < 4; r++) {
        int row = R0 + (lq << 2) + r;
        float m0 = sc[(row << 2)],     s0 = sc[(row << 2) + 1];
        float m1v = sc[(row << 2) + 2], s1v = sc[(row << 2) + 3];
        float m = fmaxf(m0, m1v);
        float sum = s0 * __expf(m0 - m) + s1v * __expf(m1v - m);
        float scale = __expf(mp0[r] - m) / sum;
#pragma unroll
        for (int nf = 0; nf < 4; nf++) {
            int cc = (ch << 6) + (nf << 4) + lr;
            int chunk = cc >> 3;
            *(unsigned short*)(Ps + row * 256 + ((chunk ^ (row & 7)) << 4) + ((lr & 7) << 1)) =
                f2bf(acc0[nf][r] * scale);
        }
        mm0[r] = m;
    }
#pragma unroll
    for (int r = 0; r < 4; r++) {
        int row = R0 + (lq << 2) + r;
        float m0 = sc[((32 + row) << 2)],     s0 = sc[((32 + row) << 2) + 1];
        float m1v = sc[((32 + row) << 2) + 2], s1v = sc[((32 + row) << 2) + 3];
        float m = fmaxf(m0, m1v);
        float sum = s0 * __expf(m0 - m) + s1v * __expf(m1v - m);
        float scale = __expf(mp1[r] - m) / sum;
#pragma unroll
        for (int nf = 0; nf < 4; nf++) {
            int cc = (ch << 6) + (nf << 4) + lr;
            int chunk = cc >> 3;
            *(unsigned short*)(PB + row * 256 + ((chunk ^ (row & 7)) << 4) + ((lr & 7) << 1)) =
                f2bf(acc1[nf][r] * scale);
        }
        mm1[r] = m;
    }
    __syncthreads();               // S6: P0/P1 visible to all waves

    int prow = R0 + lr;
    s8v pf0[4], pf1[4];
#pragma unroll
    for (int jk = 0; jk < 4; jk++) {
        pf0[jk] = *(const s8v*)(Ps + prow * 256 + ((((jk << 2) + lq) ^ (prow & 7)) << 4));
        pf1[jk] = *(const s8v*)(PB + prow * 256 + ((((jk << 2) + lq) ^ (prow & 7)) << 4));
    }
    __syncthreads();               // S6b: P1 reads done -> B1 reusable
    stageQ(B1, 1);

    f4 accB0[8], accB1[8];
#pragma unroll
    for (int ai = 0; ai < 8; ai++) { accB0[ai] = (f4){0.f,0.f,0.f,0.f}; accB1[ai] = (f4){0.f,0.f,0.f,0.f}; }

    auto mfmaB2 = [&](char* rb, int s) {
#pragma unroll
        for (int df2 = 0; df2 < 2; df2++) {
            int dr = (ch << 5) + (df2 << 4) + lr;
            int ai = (s << 1) + df2;
#pragma unroll
            for (int jk = 0; jk < 4; jk++) {
                s8v bv = *(const s8v*)(rb + (dr << 8) + ((((jk << 2) + lq) ^ (dr & 7)) << 4));
                accB0[ai] = __builtin_amdgcn_mfma_f32_16x16x32_bf16(pf0[jk], bv, accB0[ai], 0, 0, 0);
                accB1[ai] = __builtin_amdgcn_mfma_f32_16x16x32_bf16(pf1[jk], bv, accB1[ai], 0, 0, 0);
            }
        }
    };

    mfmaB2(B0, 0);
    __syncthreads();               // S7
    stageQ(B0, 2);
    mfmaB2(B1, 1);
    __syncthreads();               // S8
    stageQ(B1, 3);
    mfmaB2(B0, 2);
    __syncthreads();               // S9
    mfmaB2(B1, 3);
    __syncthreads();               // S10: bufs free

    // ---- epilogue: two 32-row passes through cq (32 KB = B0|B1) ----
    auto epiPass = [&](const f4 (&A)[8], int p) {
        float* cq = (float*)lds;
#pragma unroll
        for (int s2 = 0; s2 < 4; s2++)
#pragma unroll
            for (int df2 = 0; df2 < 2; df2++) {
                int col = (s2 << 6) + (ch << 5) + (df2 << 4) + lr;
                int ai = (s2 << 1) + df2;
                int chunk = col >> 2;
#pragma unroll
                for (int r = 0; r < 4; r++) {
                    int row = R0 + (lq << 2) + r;
                    *(float*)((char*)cq + (row << 10) + ((chunk ^ (row & 7)) << 4) + ((col & 3) << 2)) = A[ai][r];
                }
            }
        __syncthreads();
        int row = tid >> 3;
        int o = b * T_ + t0 + (p << 5) + row;
        const float* crow = ctx + o * D_;
        float* orow = out + o * 1024;
#pragma unroll
        for (int i = 0; i < 8; i++) {
            int col4 = (i << 5) + ((tid & 7) << 2);
            int chunk = col4 >> 2;
            f4 val = *(const f4*)((char*)cq + (row << 10) + ((chunk ^ (row & 7)) << 4));
            f4 cx = *(const f4*)(crow + col4);
            f4 v3 = cx * val;
            __builtin_nontemporal_store(cx, (f4*)(orow + col4));
            __builtin_nontemporal_store(val, (f4*)(orow + 256 + col4));
            __builtin_nontemporal_store(v3, (f4*)(orow + 512 + col4));
        }
    };
    epiPass(accB0, 0);
    __syncthreads();
    epiPass(accB1, 1);

    // ---- q2c partials, both groups ----
    auto q2cPart = [&](const float (&mmg)[4], int g) {
        float m16[16];
#pragma unroll
        for (int i = 0; i < 16; i++) m16[i] = __shfl(mmg[i & 3], (i >> 2) << 4);
        float mw = -1e30f;
#pragma unroll
        for (int i = 0; i < 16; i++) mw = fmaxf(mw, m16[i]);
        const float* cp = ctx + (b * T_ + t0 + (g << 5) + R0) * D_ + (ch << 7) + (l << 1);
        f2 p = (f2){0.f, 0.f};
        float sw_ = 0.f;
#pragma unroll 4
        for (int t = 0; t < 16; t++) {
            float e = __expf(m16[t] - mw);
            sw_ += e;
            f2 cv = *(const f2*)(cp + t * D_);
            p.x += e * cv.x; p.y += e * cv.y;
        }
        int tc32 = (tt << 1) | g;
        int pidx = (((b << 5) | tc32) << 1) | rg;
        *(f2*)(pq2c + (pidx << 8) + (ch << 7) + (l << 1)) = p;
        if (ch == 0 && l == 0) { pms[pidx * 2] = mw; pms[pidx * 2 + 1] = sw_; }
    };
    q2cPart(mm0, 0);
    q2cPart(mm1, 1);
}

// ---------------- K_tail: merge 64 partials -> q2c; write quarter 4 ----------------
__global__ __launch_bounds__(256) void k_tail(const float* __restrict__ ctx,
                                              const float* __restrict__ pq2c, const float* __restrict__ pms,
                                              float* __restrict__ out) {
    int b = blockIdx.x >> 5, tc = blockIdx.x & 31;
    int tid = threadIdx.x;
    const float* pm = pms + b * 128;

    float mx = -1e30f;
#pragma unroll 8
    for (int i = 0; i < 64; i++) mx = fmaxf(mx, pm[2 * i]);
    float sm = 0.f, q2 = 0.f;
#pragma unroll 4
    for (int i = 0; i < 64; i++) {
        float e = __expf(pm[2 * i] - mx);
        sm += pm[2 * i + 1] * e;
        q2 += e * pq2c[((b << 6) + i) * 256 + tid];
    }
    q2 /= sm;
    __shared__ float q2s[256];
    q2s[tid] = q2;
    __syncthreads();

    int row = tid >> 3;
    int o = b * T_ + tc * 32 + row;
    const float* crow = ctx + o * D_;
    float* orow = out + o * 1024;
#pragma unroll
    for (int i = 0; i < 8; i++) {
        int col4 = (i << 5) + ((tid & 7) << 2);
        f4 cx = *(const f4*)(crow + col4);
        f4 qv = *(const f4*)&q2s[col4];
        f4 r = cx * qv;
        __builtin_nontemporal_store(r, (f4*)(orow + 768 + col4));
    }
}

extern "C" void kernel_launch(void* const* d_in, const int* in_sizes, int n_in,
                              void* d_out, int out_size, void* d_ws, size_t ws_size,
                              hipStream_t stream) {
    const float* ctx   = (const float*)d_in[0];
    const float* query = (const float*)d_in[1];
    const float* w     = (const float*)d_in[2];
    float* out = (float*)d_out;

    unsigned short* Bqh = (unsigned short*)d_ws;        // 2 MB
    unsigned short* qTh = Bqh + B_ * J_ * D_;           // 2 MB
    float* fws = (float*)(qTh + B_ * J_ * D_);
    float* sq   = fws;                                  // 4096 floats
    float* pq2c = fws + 4096;                           // 2048*256 floats (2 MB)
    float* pms  = fws + 4096 + 2048 * 256;              // 4096 floats

    k_pre<<<B_ * 8, 256, 0, stream>>>(query, w, Bqh, sq, qTh);
    k_main<<<B_ * (T_ / 64), 256, 0, stream>>>(ctx, Bqh, qTh, sq, pq2c, pms, out);
    k_tail<<<B_ * 32, 256, 0, stream>>>(ctx, pq2c, pms, out);
}